// Round 1
// 446.735 us; speedup vs baseline: 1.0696x; 1.0696x over previous
//
#include <hip/hip_runtime.h>
#include <math.h>

#define NB 16
#define DD 256       // D (in channels)
#define LL 16384     // H*W
#define DO 256       // D_OUT

// workspace float offsets
#define WS_QKP   0                    // 8*256 qk partials
#define WS_QW2P  2048                 // 8*256 qw2 partials
#define WS_W1T   4096                 // 65536  w1t[f][o]
#define WS_VWT   (WS_W1T + 65536)     // 65536  v_wt[d][o]
#define WS_PQ    (WS_VWT + 65536)     // 16384
#define WS_M     (WS_PQ + LL)         // 16*32
#define WS_DEN   (WS_M + NB*32)       // 16*32
#define WS_NUM   (WS_DEN + NB*32)     // 16*32*256
// total ~283648 floats (~1.08 MB) of d_ws

__device__ __forceinline__ float gelu_tanh(float u) {
    float u3 = u*u*u;
    return 0.5f*u*(1.0f + tanhf(0.7978845608028654f*(u + 0.044715f*u3)));
}

// ---- K0: grid 528.
// blocks 0..7   : qk partial over o-chunk     (k_w^T q)
// blocks 8..15  : qw2 partial over o-chunk    (w2^T q)
// blocks 16..271: w1t[f][o] = w1[o][f]
// blocks 272..527: v_wt[d][o] = v_w[o][d]
// NOTE: c1=k_b.q and c2=b2.q are constant over l,n -> softmax-invariant -> dropped.
__global__ __launch_bounds__(256) void k0(const float* __restrict__ query,
        const float* __restrict__ k_w, const float* __restrict__ w2,
        const float* __restrict__ w1, const float* __restrict__ v_w,
        float* __restrict__ ws) {
    int t = threadIdx.x, b = blockIdx.x;
    if (b < 16) {
        bool is_k = (b < 8);
        int c = b & 7;
        const float* M = is_k ? k_w : w2;
        float a = 0.f;
        #pragma unroll
        for (int oi = 0; oi < 32; ++oi) {
            int o = c*32 + oi;
            a += M[o*DD + t] * query[o];    // row coalesced, query[o] scalar-load
        }
        ws[(is_k ? WS_QKP : WS_QW2P) + c*256 + t] = a;
    } else if (b < 272) {
        int f = b - 16;
        ws[WS_W1T + f*DO + t] = w1[t*DO + f];
    } else {
        int d = b - 272;
        ws[WS_VWT + d*DO + t] = v_w[t*DD + d];
    }
}

// ---- K1: pq[l] = gelu(feats[l] @ w1^T + b1) . qw2.  grid 512, 32 l per block.
// featsT layout [256 f][36 pad] so the 8 per-wave feats values are one contiguous
// 32B chunk -> 2 broadcast ds_read_b128 instead of 8 scalar broadcasts per f.
__global__ __launch_bounds__(256) void k1_pq(const float* __restrict__ Wr,
        const float* __restrict__ b1, float* __restrict__ ws) {
    __shared__ __align__(16) float featsT[256*36];   // 36 KB
    __shared__ __align__(16) float wbuf[32*256];     // 32 KB
    int t = threadIdx.x;
    int w = t >> 6, lane = t & 63;
    int l0 = blockIdx.x * 32;
    int r = t & 127;
    float wr0 = Wr[r*2], wr1 = Wr[r*2+1];
    bool is_cos = (t < 128);          // wave-uniform branch
    #pragma unroll 8
    for (int lr = 0; lr < 32; ++lr) {
        int l = l0 + lr;
        int i = l >> 7, j = l & 127;
        float y = -1.0f + (2.0f/127.0f)*(float)i;
        float xg = -1.0f + (2.0f/127.0f)*(float)j;
        float p = y*wr0 + xg*wr1;
        featsT[t*36 + lr] = (is_cos ? cosf(p) : sinf(p)) * 0.0625f;  // /sqrt(256)
    }
    int o4 = lane * 4;                // each wave covers all 256 o; wave owns 8 l's
    float z[8][4];
    #pragma unroll
    for (int a = 0; a < 8; ++a) { z[a][0]=0.f; z[a][1]=0.f; z[a][2]=0.f; z[a][3]=0.f; }
    // qw2[o4..o4+3] = sum of 8 partials
    float4 qwv; qwv.x = 0.f; qwv.y = 0.f; qwv.z = 0.f; qwv.w = 0.f;
    #pragma unroll
    for (int c = 0; c < 8; ++c) {
        float4 p = *(const float4*)(ws + WS_QW2P + c*256 + o4);
        qwv.x += p.x; qwv.y += p.y; qwv.z += p.z; qwv.w += p.w;
    }
    for (int fc = 0; fc < 8; ++fc) {
        // stage w1t[fc*32 .. +31][:] into LDS (coalesced float4)
        #pragma unroll
        for (int i2 = 0; i2 < 8; ++i2) {
            int idx = i2*256 + t;
            int fl = idx >> 6;
            int c = (idx & 63) * 4;
            *(float4*)(wbuf + fl*256 + c) =
                *(const float4*)(ws + WS_W1T + (fc*32+fl)*DO + c);
        }
        __syncthreads();              // stage done (covers featsT on first iter)
        for (int fl = 0; fl < 32; ++fl) {
            float4 wv = *(const float4*)(wbuf + fl*256 + o4);   // conflict-free b128
            const float* fr = featsT + (fc*32+fl)*36 + w*8;     // 16B-aligned
            float4 fa = *(const float4*)(fr);                   // broadcast b128
            float4 fb = *(const float4*)(fr+4);                 // broadcast b128
            float fv[8] = {fa.x,fa.y,fa.z,fa.w,fb.x,fb.y,fb.z,fb.w};
            #pragma unroll
            for (int lr = 0; lr < 8; ++lr) {
                z[lr][0] += fv[lr]*wv.x; z[lr][1] += fv[lr]*wv.y;
                z[lr][2] += fv[lr]*wv.z; z[lr][3] += fv[lr]*wv.w;
            }
        }
        __syncthreads();
    }
    float4 b1v = *(const float4*)(b1 + o4);
    #pragma unroll
    for (int lr = 0; lr < 8; ++lr) {
        float pp = gelu_tanh(z[lr][0]+b1v.x)*qwv.x + gelu_tanh(z[lr][1]+b1v.y)*qwv.y
                 + gelu_tanh(z[lr][2]+b1v.z)*qwv.z + gelu_tanh(z[lr][3]+b1v.w)*qwv.w;
        for (int off = 32; off > 0; off >>= 1) pp += __shfl_xor(pp, off);
        if (lane == 0) ws[WS_PQ + l0 + w*8 + lr] = pp;
    }
}

// ---- K2: single pass over x. grid 512 = (n=bid>>5, lb=bid&31), 512 l per block,
// 8 tiles of 64 l. Online softmax partials per block.
// T14 issue-early: next tile's 16 float4 loads issue before phase S, LDS-write
// after the post-N barrier -> HBM flows during compute.
__global__ __launch_bounds__(256) void k2_main(const float* __restrict__ x,
        float* __restrict__ ws) {
    __shared__ __align__(16) float tile[DD*65]; // 65-stride: conflict-free (~65 KB)
    __shared__ float qk_s[DD];
    __shared__ float e_s[64];
    __shared__ float part[256];
    __shared__ float m_s, den_s, sc_s;
    int t = threadIdx.x;
    int n = blockIdx.x >> 5, lb = blockIdx.x & 31;
    const float* xb = x + (size_t)n * DD * LL;
    float aqk = 0.f;
    #pragma unroll
    for (int c = 0; c < 8; ++c) aqk += ws[WS_QKP + c*256 + t];
    qk_s[t] = aqk;
    if (t == 0) { m_s = -INFINITY; den_s = 0.f; sc_s = 0.f; }
    float num = 0.f;                  // thread t accumulates num[d=t]
    int w = t >> 6, lane = t & 63;
    int dld = t >> 4;
    int li = (t & 15) * 4;
    float4 v[16];
    // prologue: tile 0
    #pragma unroll
    for (int i2 = 0; i2 < 16; ++i2)
        v[i2] = *(const float4*)(xb + (size_t)(i2*16 + dld)*LL + lb*512 + li);
    __syncthreads();                  // qk_s / m_s ready
    #pragma unroll
    for (int i2 = 0; i2 < 16; ++i2) {
        float* dst = tile + (i2*16 + dld)*65 + li;
        dst[0]=v[i2].x; dst[1]=v[i2].y; dst[2]=v[i2].z; dst[3]=v[i2].w;
    }
    __syncthreads();
    for (int tb = 0; tb < 8; ++tb) {
        int l0 = lb*512 + tb*64;
        // issue next tile's loads early (regs), written to LDS after last use
        if (tb < 7) {
            int l0n = l0 + 64;
            #pragma unroll
            for (int i2 = 0; i2 < 16; ++i2)
                v[i2] = *(const float4*)(xb + (size_t)(i2*16 + dld)*LL + l0n + li);
        }
        // phase S: wave w sums d-range [w*64, w*64+64) for l=lane
        float acc = 0.f;
        int dbase = w*64;
        #pragma unroll 8
        for (int i2 = 0; i2 < 64; ++i2)
            acc += tile[(dbase+i2)*65 + lane] * qk_s[dbase+i2];
        part[t] = acc;
        __syncthreads();
        if (t < 64) {   // wave 0 finalizes scores for this tile
            float dot = part[t] + part[64+t] + part[128+t] + part[192+t];
            float score = (dot + ws[WS_PQ + l0 + t]) * 0.0625f;
            float mc = score;
            for (int off=32; off>0; off>>=1) mc = fmaxf(mc, __shfl_xor(mc, off));
            float mold = m_s;
            float mnew = fmaxf(mold, mc);
            float e = expf(score - mnew);
            e_s[t] = e;
            float dc = e;
            for (int off=32; off>0; off>>=1) dc += __shfl_xor(dc, off);
            if (t == 0) {
                float sc = expf(mold - mnew);   // first tile: exp(-inf)=0
                den_s = den_s*sc + dc;
                m_s = mnew;
                sc_s = sc;
            }
        }
        __syncthreads();
        // phase N: thread t = d; banks (t+l)%32 -> conflict-free
        float sc = sc_s;
        float acc2 = 0.f;
        #pragma unroll 8
        for (int l = 0; l < 64; ++l)
            acc2 += e_s[l] * tile[t*65 + l];
        num = num*sc + acc2;
        __syncthreads();              // all waves done reading tile
        if (tb < 7) {
            #pragma unroll
            for (int i2 = 0; i2 < 16; ++i2) {
                float* dst = tile + (i2*16 + dld)*65 + li;
                dst[0]=v[i2].x; dst[1]=v[i2].y; dst[2]=v[i2].z; dst[3]=v[i2].w;
            }
        }
        __syncthreads();              // tile ready
    }
    int pb = n*32 + lb;
    ws[WS_NUM + pb*256 + t] = num;
    if (t == 0) { ws[WS_M + pb] = m_s; ws[WS_DEN + pb] = den_s; }
}

// ---- K3: combine partials per n, then out[n,o] = v_w[o,:].s + v_b[o]. grid 16.
__global__ __launch_bounds__(256) void k3_final(const float* __restrict__ ws,
        const float* __restrict__ v_b, float* __restrict__ out) {
    __shared__ float s_s[DD];
    int t = threadIdx.x, n = blockIdx.x;
    float m = -INFINITY;
    #pragma unroll
    for (int lb = 0; lb < 32; ++lb) m = fmaxf(m, ws[WS_M + n*32 + lb]);
    float den = 0.f;
    #pragma unroll
    for (int lb = 0; lb < 32; ++lb)
        den += ws[WS_DEN + n*32 + lb] * expf(ws[WS_M + n*32 + lb] - m);
    float sacc = 0.f;
    #pragma unroll 4
    for (int lb = 0; lb < 32; ++lb) {
        float sc = expf(ws[WS_M + n*32 + lb] - m);
        sacc += ws[WS_NUM + (n*32+lb)*256 + t] * sc;   // coalesced
    }
    s_s[t] = sacc / den;
    __syncthreads();
    float acc = v_b[t];
    #pragma unroll 8
    for (int d = 0; d < DD; ++d)
        acc += ws[WS_VWT + d*DO + t] * s_s[d];         // coalesced, s broadcast
    out[n*DO + t] = acc;
}

extern "C" void kernel_launch(void* const* d_in, const int* in_sizes, int n_in,
                              void* d_out, int out_size, void* d_ws, size_t ws_size,
                              hipStream_t stream) {
    const float* x     = (const float*)d_in[0];
    const float* query = (const float*)d_in[1];
    const float* k_w   = (const float*)d_in[2];
    const float* v_w   = (const float*)d_in[4];
    const float* v_b   = (const float*)d_in[5];
    const float* Wr    = (const float*)d_in[6];
    const float* w1    = (const float*)d_in[7];
    const float* b1    = (const float*)d_in[8];
    const float* w2    = (const float*)d_in[9];
    float* ws  = (float*)d_ws;
    float* out = (float*)d_out;

    k0<<<528, 256, 0, stream>>>(query, k_w, w2, w1, v_w, ws);
    k1_pq<<<512, 256, 0, stream>>>(Wr, b1, ws);
    k2_main<<<512, 256, 0, stream>>>(x, ws);
    k3_final<<<16, 256, 0, stream>>>(ws, v_b, out);
}